// Round 6
// baseline (608.475 us; speedup 1.0000x reference)
//
#include <hip/hip_runtime.h>

// ThreePhaseTerm: sparse chemistry RHS assembly on MI355X.
//
// Round-6 structure (fix gainloss latency-bind + compact + fewer launches):
//   - thread = batch everywhere (r5's transposed tables yT[s][b], wT[s][b];
//     wT rows 800/801/802 = 1 / k_s2m / k_m2s; unified edge term
//     a_s * exp2(beta*lt2 + gamma*nivt) * yT[ia][b] * wT[ib][b]).
//   - gl streams COMPACTED at pack time (only p in [200,500) survives, ~37.5%).
//   - both consumers: many small blocks, LDS-staged edge chunk (broadcast
//     reads), readfirstlane-scalarized indices, manual 4x unroll -> 8
//     independent coalesced loads in flight; full occupancy.
//   - final: p carried in record bits[20..29]; uniform 120-edge chunks,
//     flush-on-p-change via coalesced atomicAdd into outT[p][b]; tiled
//     transpose outT -> out at the end.
//   - 10 kernels + 1 memset (contiguous zero region).

constexpr int B_    = 256;
constexpr int S_    = 800;
constexpr int E1_   = 60000;
constexpr int E2_   = 180000;
constexpr int ET_   = E1_ + E2_;      // 240000 final edges
constexpr int EGL_  = 120000;         // gain/loss edges before compaction
constexpr int NSMT_ = 600;
constexpr float LOG2E_ = 1.4426950408889634f;
constexpr float EPS_   = 1e-30f;
constexpr int PAD   = 16;             // int stride for sort counters
constexpr int CAP_  = 32768;          // per-stream gl capacity (exp ~22500)
constexpr int NBF_  = 2000;           // final blocks
constexpr int EPB_  = ET_ / NBF_;     // 120 edges per final block (exact)
constexpr int NBGL_ = 1024;           // gainloss blocks
constexpr int NSL_  = 8;              // partial slices for part accumulation
// unified second-operand rows in wT
constexpr int IB_ONE = 800, IB_KS = 801, IB_KM = 802, WROWS = 804;

#if defined(__has_builtin)
#if __has_builtin(__builtin_amdgcn_exp2f)
#define FAST_EXP2(x) __builtin_amdgcn_exp2f(x)
#endif
#endif
#ifndef FAST_EXP2
#define FAST_EXP2(x) exp2f(x)
#endif

// ---------------------------------------------------------------------------
// Sort phase A: histogram of product indices (padded counters, pre-zeroed).
// ---------------------------------------------------------------------------
__global__ __launch_bounds__(256) void hist_kernel(
    const int* __restrict__ p1, const int* __restrict__ p2,
    int* __restrict__ cnt)
{
    int e = blockIdx.x * 256 + threadIdx.x;
    if (e < E1_)      atomicAdd(&cnt[p1[e] * PAD], 1);
    else if (e < ET_) atomicAdd(&cnt[p2[e - E1_] * PAD], 1);
}

// ---------------------------------------------------------------------------
// Sort phase B: exclusive scan of 800 bins (one block); rank shares cnt
// storage (all reads happen before any write).
// ---------------------------------------------------------------------------
__global__ __launch_bounds__(1024) void scan_kernel(int* __restrict__ cntrank)
{
    __shared__ int sc[1024];
    int t = threadIdx.x;
    sc[t] = (t < S_) ? cntrank[t * PAD] : 0;
    __syncthreads();
    for (int off = 1; off < 1024; off <<= 1) {
        int v = (t >= off) ? sc[t - off] : 0;
        __syncthreads();
        sc[t] += v;
        __syncthreads();
    }
    if (t < S_) cntrank[t * PAD] = t ? sc[t - 1] : 0;
}

// ---------------------------------------------------------------------------
// Sort phase C: reorder+pack BOTH final edge lists into sorted stream.
// bits = ia | ib<<10 | p<<20 ; ib in {rb (2nd order), 800, 801, 802}.
// ---------------------------------------------------------------------------
__global__ __launch_bounds__(256) void reorder_kernel(
    const float* __restrict__ alpha, const float* __restrict__ beta,
    const float* __restrict__ gam,
    const int* __restrict__ k1, const int* __restrict__ r1,
    const int* __restrict__ p1, const int* __restrict__ s1,
    const int* __restrict__ k2, const int* __restrict__ ra2,
    const int* __restrict__ rb2, const int* __restrict__ p2,
    const int* __restrict__ s2,
    int* __restrict__ rank, float4* __restrict__ sorted)
{
    int e = blockIdx.x * 256 + threadIdx.x;
    if (e >= ET_) return;
    int kk, ia, ib, pp, ss;
    if (e < E1_) {
        kk = k1[e]; ia = r1[e]; pp = p1[e]; ss = s1[e]; ib = IB_ONE;
    } else {
        int i = e - E1_;
        kk = k2[i]; ia = ra2[i]; ib = rb2[i]; pp = p2[i]; ss = s2[i];
    }
    float a = alpha[kk], b = beta[kk], g = gam[kk];
    if (e < E1_ && kk < 2 * NSMT_) {
        ib = (kk < NSMT_) ? IB_KS : IB_KM;
        a = 1.0f; b = 0.0f; g = 0.0f;       // exp2(0)=1; coeff via wT row
    }
    float a_s = ss ? a : -a;
    int bits = ia | (ib << 10) | (pp << 20);
    int slot = atomicAdd(&rank[pp * PAD], 1);
    sorted[slot] = make_float4(a_s, b, g, __int_as_float(bits));
}

// ---------------------------------------------------------------------------
// Transpose in: yT[s][b] = y[b][s]; wT[s][b] = y[b][s]*den[b]; wT[800][b]=1.
// ---------------------------------------------------------------------------
__global__ __launch_bounds__(256) void transpose_kernel(
    const float* __restrict__ y, const float* __restrict__ den_gas,
    float* __restrict__ yT, float* __restrict__ wT)
{
    __shared__ float tile[32][33];
    const int sb = blockIdx.x % 25, bb = blockIdx.x / 25;
    const int tx = threadIdx.x & 31, ty = threadIdx.x >> 5;   // ty in [0,8)
    const int s0 = sb * 32, b0 = bb * 32;

    #pragma unroll
    for (int j = 0; j < 4; ++j) {
        int bl = ty + 8 * j;
        tile[bl][tx] = y[(b0 + bl) * S_ + s0 + tx];    // coalesced along s
    }
    __syncthreads();
    const float d = den_gas[b0 + tx];
    #pragma unroll
    for (int j = 0; j < 4; ++j) {
        int sl = ty + 8 * j;
        float v = tile[tx][sl];
        yT[(s0 + sl) * B_ + b0 + tx] = v;              // coalesced along b
        wT[(s0 + sl) * B_ + b0 + tx] = v * d;
    }
    if (blockIdx.x == 0) wT[IB_ONE * B_ + threadIdx.x] = 1.0f;
}

// ---------------------------------------------------------------------------
// Pack+compact gain/loss streams: keep only p in [200,500).
// Segments: [0,15k)=g1, [15k,60k)=g2, [60k,75k)=l1, [75k,120k)=l2.
// ---------------------------------------------------------------------------
__global__ __launch_bounds__(256) void packgl_kernel(
    const float* __restrict__ alpha, const float* __restrict__ beta,
    const float* __restrict__ gam,
    const int* __restrict__ k1g, const int* __restrict__ r1g,
    const int* __restrict__ p1g, const int* __restrict__ s1g,
    const int* __restrict__ k2g, const int* __restrict__ ra2g,
    const int* __restrict__ rb2g, const int* __restrict__ p2g,
    const int* __restrict__ s2g,
    const int* __restrict__ k1l, const int* __restrict__ r1l,
    const int* __restrict__ p1l, const int* __restrict__ s1l,
    const int* __restrict__ k2l, const int* __restrict__ ra2l,
    const int* __restrict__ rb2l, const int* __restrict__ p2l,
    const int* __restrict__ s2l,
    int* __restrict__ glcnt, float4* __restrict__ glG, float4* __restrict__ glL)
{
    int e = blockIdx.x * 256 + threadIdx.x;
    if (e >= EGL_) return;
    int kk, ia, ib, pp, ss, gl;
    if (e < 15000)      { int i = e;         kk = k1g[i]; ia = r1g[i];  ib = IB_ONE;   pp = p1g[i]; ss = s1g[i]; gl = 0; }
    else if (e < 60000) { int i = e - 15000; kk = k2g[i]; ia = ra2g[i]; ib = rb2g[i];  pp = p2g[i]; ss = s2g[i]; gl = 0; }
    else if (e < 75000) { int i = e - 60000; kk = k1l[i]; ia = r1l[i];  ib = IB_ONE;   pp = p1l[i]; ss = s1l[i]; gl = 1; }
    else                { int i = e - 75000; kk = k2l[i]; ia = ra2l[i]; ib = rb2l[i];  pp = p2l[i]; ss = s2l[i]; gl = 1; }
    if (pp < 200 || pp >= 500) return;       // contributes exactly 0
    float a = alpha[kk], b = beta[kk], g = gam[kk];
    float a_s = ss ? a : -a;
    int bits = ia | (ib << 10);
    int slot = atomicAdd(&glcnt[gl], 1);
    (gl ? glL : glG)[slot] = make_float4(a_s, b, g, __int_as_float(bits));
}

// ---------------------------------------------------------------------------
// unified edge term (indices scalarized via readfirstlane; loads coalesced)
// ---------------------------------------------------------------------------
__device__ __forceinline__ float edge_term(
    float4 q, int t, const float* __restrict__ yT, const float* __restrict__ wT,
    float lt2, float nivt)
{
    int bu = __builtin_amdgcn_readfirstlane(__float_as_int(q.w));
    int ia = bu & 1023, ib = (bu >> 10) & 1023;
    return q.x * FAST_EXP2(fmaf(q.y, lt2, q.z * nivt))
         * yT[ia * B_ + t] * wT[ib * B_ + t];
}

// ---------------------------------------------------------------------------
// K1: gain/loss sums.  grid = NBGL_; thread = batch; LDS-staged chunks;
// sliced atomics into part_sl[NSL_][2*B].
// ---------------------------------------------------------------------------
__global__ __launch_bounds__(256) void gainloss_kernel(
    const float* __restrict__ T_gas,
    const float* __restrict__ yT, const float* __restrict__ wT,
    const float4* __restrict__ glG, const float4* __restrict__ glL,
    const int* __restrict__ glcnt,
    float* __restrict__ part_sl)
{
    __shared__ float4 tG[CAP_ / NBGL_], tL[CAP_ / NBGL_];   // 32 each
    const int t = threadIdx.x, c = blockIdx.x;
    const int nG = glcnt[0], nL = glcnt[1];
    const int cG = (nG + NBGL_ - 1) >> 10;
    const int cL = (nL + NBGL_ - 1) >> 10;
    const int g0 = c * cG, gn = min(nG, g0 + cG) - g0;
    const int l0 = c * cL, ln = min(nL, l0 + cL) - l0;
    for (int i = t; i < gn; i += 256) tG[i] = glG[g0 + i];
    for (int i = t; i < ln; i += 256) tL[i] = glL[l0 + i];
    __syncthreads();

    const float T    = T_gas[t];
    const float lt2  = log2f(T * (1.0f / 300.0f));
    const float nivt = -LOG2E_ / T;

    float gain = 0.f, loss = 0.f;
    #pragma unroll 4
    for (int i = 0; i < gn; ++i) gain += edge_term(tG[i], t, yT, wT, lt2, nivt);
    #pragma unroll 4
    for (int i = 0; i < ln; ++i) loss += edge_term(tL[i], t, yT, wT, lt2, nivt);

    float* sl = part_sl + (c & (NSL_ - 1)) * (2 * B_);
    atomicAdd(&sl[2 * t + 0], gain);
    atomicAdd(&sl[2 * t + 1], loss);
}

// ---------------------------------------------------------------------------
// ksm: per-batch k_s2m/k_m2s -> wT rows 801/802.  grid = B_ blocks, 64 thr.
// ---------------------------------------------------------------------------
__global__ __launch_bounds__(64) void ksm_kernel(
    const float* __restrict__ y, const float* __restrict__ part_sl,
    float* __restrict__ wT)
{
    const int b = blockIdx.x, lane = threadIdx.x;
    float vs = 0.f, vm = 0.f;
    #pragma unroll
    for (int j = 0; j < 5; ++j) {
        int i = lane + 64 * j;
        if (i < 300) { vs += y[b * S_ + 200 + i]; vm += y[b * S_ + 500 + i]; }
    }
    #pragma unroll
    for (int o = 32; o > 0; o >>= 1) {
        vs += __shfl_down(vs, o, 64);
        vm += __shfl_down(vm, o, 64);
    }
    if (lane == 0) {
        float gain = 0.f, loss = 0.f;
        #pragma unroll
        for (int s = 0; s < NSL_; ++s) {
            gain += part_sl[s * (2 * B_) + 2 * b + 0];
            loss += part_sl[s * (2 * B_) + 2 * b + 1];
        }
        float nl = 1e-2f * (vs + vm);
        float decay = fminf(2.0f / fmaxf(nl, EPS_), 1.0f);
        wT[IB_KS * B_ + b] = gain / fmaxf(vs, EPS_);
        wT[IB_KM * B_ + b] = loss / fmaxf(vm, EPS_) * decay;
    }
}

// ---------------------------------------------------------------------------
// K2: final RHS.  grid = NBF_ uniform 120-edge chunks of the sorted stream;
// thread = batch; LDS-staged chunk; flush-on-p-change into outT[p][b]
// (coalesced atomicAdd; outT pre-zeroed).
// ---------------------------------------------------------------------------
__global__ __launch_bounds__(256) void final_kernel(
    const float* __restrict__ T_gas,
    const float* __restrict__ yT, const float* __restrict__ wT,
    const float4* __restrict__ sorted,
    float* __restrict__ outT)
{
    __shared__ float4 tile[EPB_];
    const int t = threadIdx.x, c = blockIdx.x;
    const int e0 = c * EPB_;
    for (int i = t; i < EPB_; i += 256) tile[i] = sorted[e0 + i];
    __syncthreads();

    const float T    = T_gas[t];
    const float lt2  = log2f(T * (1.0f / 300.0f));
    const float nivt = -LOG2E_ / T;

    int pcur = -1;
    float acc = 0.f;
    #pragma unroll 1
    for (int i = 0; i < EPB_; i += 4) {
        float4 q0 = tile[i + 0], q1 = tile[i + 1];
        float4 q2 = tile[i + 2], q3 = tile[i + 3];
        int b0 = __builtin_amdgcn_readfirstlane(__float_as_int(q0.w));
        int b1 = __builtin_amdgcn_readfirstlane(__float_as_int(q1.w));
        int b2 = __builtin_amdgcn_readfirstlane(__float_as_int(q2.w));
        int b3 = __builtin_amdgcn_readfirstlane(__float_as_int(q3.w));
        // 8 independent coalesced loads issued together
        float y0 = yT[(b0 & 1023) * B_ + t], w0 = wT[((b0 >> 10) & 1023) * B_ + t];
        float y1 = yT[(b1 & 1023) * B_ + t], w1 = wT[((b1 >> 10) & 1023) * B_ + t];
        float y2 = yT[(b2 & 1023) * B_ + t], w2 = wT[((b2 >> 10) & 1023) * B_ + t];
        float y3 = yT[(b3 & 1023) * B_ + t], w3 = wT[((b3 >> 10) & 1023) * B_ + t];
        float t0 = q0.x * FAST_EXP2(fmaf(q0.y, lt2, q0.z * nivt)) * y0 * w0;
        float t1 = q1.x * FAST_EXP2(fmaf(q1.y, lt2, q1.z * nivt)) * y1 * w1;
        float t2 = q2.x * FAST_EXP2(fmaf(q2.y, lt2, q2.z * nivt)) * y2 * w2;
        float t3 = q3.x * FAST_EXP2(fmaf(q3.y, lt2, q3.z * nivt)) * y3 * w3;
        int p0 = b0 >> 20, p1 = b1 >> 20, p2 = b2 >> 20, p3 = b3 >> 20;
        if (p0 != pcur) { if (pcur >= 0) atomicAdd(&outT[pcur * B_ + t], acc); acc = 0.f; pcur = p0; }
        acc += t0;
        if (p1 != pcur) { atomicAdd(&outT[pcur * B_ + t], acc); acc = 0.f; pcur = p1; }
        acc += t1;
        if (p2 != pcur) { atomicAdd(&outT[pcur * B_ + t], acc); acc = 0.f; pcur = p2; }
        acc += t2;
        if (p3 != pcur) { atomicAdd(&outT[pcur * B_ + t], acc); acc = 0.f; pcur = p3; }
        acc += t3;
    }
    atomicAdd(&outT[pcur * B_ + t], acc);
}

// ---------------------------------------------------------------------------
// Transpose out: out[b][s] = outT[s][b].
// ---------------------------------------------------------------------------
__global__ __launch_bounds__(256) void transpose_out_kernel(
    const float* __restrict__ outT, float* __restrict__ out)
{
    __shared__ float tile[32][33];
    const int sb = blockIdx.x % 25, bb = blockIdx.x / 25;
    const int tx = threadIdx.x & 31, ty = threadIdx.x >> 5;
    const int s0 = sb * 32, b0 = bb * 32;

    #pragma unroll
    for (int j = 0; j < 4; ++j) {
        int sl = ty + 8 * j;
        tile[sl][tx] = outT[(s0 + sl) * B_ + b0 + tx];   // coalesced along b
    }
    __syncthreads();
    #pragma unroll
    for (int j = 0; j < 4; ++j) {
        int bl = ty + 8 * j;
        out[(b0 + bl) * S_ + s0 + tx] = tile[tx][bl];    // coalesced along s
    }
}

// ---------------------------------------------------------------------------
extern "C" void kernel_launch(void* const* d_in, const int* in_sizes, int n_in,
                              void* d_out, int out_size, void* d_ws, size_t ws_size,
                              hipStream_t stream) {
    const float* y       = (const float*)d_in[1];
    const float* den_gas = (const float*)d_in[2];
    const float* T_gas   = (const float*)d_in[3];
    const float* alpha   = (const float*)d_in[4];
    const float* beta    = (const float*)d_in[5];
    const float* gam     = (const float*)d_in[6];
    const int* k1  = (const int*)d_in[7];
    const int* r1  = (const int*)d_in[8];
    const int* p1  = (const int*)d_in[9];
    const int* s1  = (const int*)d_in[10];
    const int* k2  = (const int*)d_in[11];
    const int* ra2 = (const int*)d_in[12];
    const int* rb2 = (const int*)d_in[13];
    const int* p2  = (const int*)d_in[14];
    const int* s2  = (const int*)d_in[15];
    const int* k1g  = (const int*)d_in[16];
    const int* r1g  = (const int*)d_in[17];
    const int* p1g  = (const int*)d_in[18];
    const int* s1g  = (const int*)d_in[19];
    const int* k2g  = (const int*)d_in[20];
    const int* ra2g = (const int*)d_in[21];
    const int* rb2g = (const int*)d_in[22];
    const int* p2g  = (const int*)d_in[23];
    const int* s2g  = (const int*)d_in[24];
    const int* k1l  = (const int*)d_in[25];
    const int* r1l  = (const int*)d_in[26];
    const int* p1l  = (const int*)d_in[27];
    const int* s1l  = (const int*)d_in[28];
    const int* k2l  = (const int*)d_in[29];
    const int* ra2l = (const int*)d_in[30];
    const int* rb2l = (const int*)d_in[31];
    const int* p2l  = (const int*)d_in[32];
    const int* s2l  = (const int*)d_in[33];

    // workspace layout (~7.4 MB); ZERO region is contiguous (one memset)
    char* wsp = (char*)d_ws;
    size_t off = 0;
    float4* sorted = (float4*)(wsp + off); off += (size_t)ET_ * 16;        // 3,840,000
    float4* glG    = (float4*)(wsp + off); off += (size_t)CAP_ * 16;       //   524,288
    float4* glL    = (float4*)(wsp + off); off += (size_t)CAP_ * 16;       //   524,288
    float*  yT     = (float*)(wsp + off);  off += (size_t)S_ * B_ * 4;     //   819,200
    float*  wT     = (float*)(wsp + off);  off += (size_t)WROWS * B_ * 4;  //   823,296
    // ---- zero region start ----
    size_t zoff = off;
    float*  outT    = (float*)(wsp + off); off += (size_t)S_ * B_ * 4;     //   819,200
    int*    cntrank = (int*)(wsp + off);   off += (size_t)S_ * PAD * 4;    //    51,200
    float*  part_sl = (float*)(wsp + off); off += (size_t)NSL_ * 2 * B_ * 4; //  16,384
    int*    glcnt   = (int*)(wsp + off);   off += 64;
    size_t zbytes = off - zoff;

    float* out = (float*)d_out;

    hipMemsetAsync(wsp + zoff, 0, zbytes, stream);

    // counting sort of final edges by product p (batch-independent)
    hist_kernel<<<(ET_ + 255) / 256, 256, 0, stream>>>(p1, p2, cntrank);
    scan_kernel<<<1, 1024, 0, stream>>>(cntrank);
    reorder_kernel<<<(ET_ + 255) / 256, 256, 0, stream>>>(
        alpha, beta, gam, k1, r1, p1, s1, k2, ra2, rb2, p2, s2, cntrank, sorted);

    // transposed y / w tables
    transpose_kernel<<<200, 256, 0, stream>>>(y, den_gas, yT, wT);

    // compacted gain/loss streams
    packgl_kernel<<<(EGL_ + 255) / 256, 256, 0, stream>>>(
        alpha, beta, gam,
        k1g, r1g, p1g, s1g, k2g, ra2g, rb2g, p2g, s2g,
        k1l, r1l, p1l, s1l, k2l, ra2l, rb2l, p2l, s2l,
        glcnt, glG, glL);

    // gain/loss scalars
    gainloss_kernel<<<NBGL_, 256, 0, stream>>>(T_gas, yT, wT, glG, glL, glcnt, part_sl);
    ksm_kernel<<<B_, 64, 0, stream>>>(y, part_sl, wT);

    // final assembly into outT, then transpose to out
    final_kernel<<<NBF_, 256, 0, stream>>>(T_gas, yT, wT, sorted, outT);
    transpose_out_kernel<<<200, 256, 0, stream>>>(outT, out);
}

// Round 7
// 101.556 us; speedup vs baseline: 5.9915x; 5.9915x over previous
//
#include <hip/hip_runtime.h>

// ThreePhaseTerm: sparse chemistry RHS assembly on MI355X.
//
// Round-7 = round-6 with the packgl compaction fixed: round 6's per-thread
// atomicAdd on TWO global counters serialized ~45K returning RMWs on one
// cacheline (512us, VALUBusy 0.017%). Now: per-wave ballot + LDS scan +
// ONE atomicAdd per block per stream; slot = block base + wave prefix +
// ballot prefix. Everything else unchanged from round 6:
//   - thread = batch; transposed tables yT[s][b], wT[s][b]
//     (wT rows 800/801/802 = 1 / k_s2m / k_m2s); unified edge term
//     a_s * exp2(beta*lt2 + gamma*nivt) * yT[ia][b] * wT[ib][b].
//   - final: counting-sorted edge stream, p in record bits[20..29], uniform
//     120-edge LDS-staged chunks, flush-on-p-change atomicAdd into outT[p][b],
//     tiled transpose at the end.
//   - gainloss: compacted streams (p in [200,500) only), LDS-staged chunks,
//     sliced partial atomics.

constexpr int B_    = 256;
constexpr int S_    = 800;
constexpr int E1_   = 60000;
constexpr int E2_   = 180000;
constexpr int ET_   = E1_ + E2_;      // 240000 final edges
constexpr int EGL_  = 120000;         // gain/loss edges before compaction
constexpr int NSMT_ = 600;
constexpr float LOG2E_ = 1.4426950408889634f;
constexpr float EPS_   = 1e-30f;
constexpr int PAD   = 16;             // int stride for sort counters
constexpr int CAP_  = 32768;          // per-stream gl capacity (exp ~22500)
constexpr int NBF_  = 2000;           // final blocks
constexpr int EPB_  = ET_ / NBF_;     // 120 edges per final block (exact)
constexpr int NBGL_ = 1024;           // gainloss blocks
constexpr int NSL_  = 8;              // partial slices for part accumulation
// unified second-operand rows in wT
constexpr int IB_ONE = 800, IB_KS = 801, IB_KM = 802, WROWS = 804;

#if defined(__has_builtin)
#if __has_builtin(__builtin_amdgcn_exp2f)
#define FAST_EXP2(x) __builtin_amdgcn_exp2f(x)
#endif
#endif
#ifndef FAST_EXP2
#define FAST_EXP2(x) exp2f(x)
#endif

// ---------------------------------------------------------------------------
// Sort phase A: histogram of product indices (padded counters, pre-zeroed).
// ---------------------------------------------------------------------------
__global__ __launch_bounds__(256) void hist_kernel(
    const int* __restrict__ p1, const int* __restrict__ p2,
    int* __restrict__ cnt)
{
    int e = blockIdx.x * 256 + threadIdx.x;
    if (e < E1_)      atomicAdd(&cnt[p1[e] * PAD], 1);
    else if (e < ET_) atomicAdd(&cnt[p2[e - E1_] * PAD], 1);
}

// ---------------------------------------------------------------------------
// Sort phase B: exclusive scan of 800 bins (one block); rank shares cnt
// storage (all reads happen before any write).
// ---------------------------------------------------------------------------
__global__ __launch_bounds__(1024) void scan_kernel(int* __restrict__ cntrank)
{
    __shared__ int sc[1024];
    int t = threadIdx.x;
    sc[t] = (t < S_) ? cntrank[t * PAD] : 0;
    __syncthreads();
    for (int off = 1; off < 1024; off <<= 1) {
        int v = (t >= off) ? sc[t - off] : 0;
        __syncthreads();
        sc[t] += v;
        __syncthreads();
    }
    if (t < S_) cntrank[t * PAD] = t ? sc[t - 1] : 0;
}

// ---------------------------------------------------------------------------
// Sort phase C: reorder+pack BOTH final edge lists into sorted stream.
// bits = ia | ib<<10 | p<<20 ; ib in {rb (2nd order), 800, 801, 802}.
// ---------------------------------------------------------------------------
__global__ __launch_bounds__(256) void reorder_kernel(
    const float* __restrict__ alpha, const float* __restrict__ beta,
    const float* __restrict__ gam,
    const int* __restrict__ k1, const int* __restrict__ r1,
    const int* __restrict__ p1, const int* __restrict__ s1,
    const int* __restrict__ k2, const int* __restrict__ ra2,
    const int* __restrict__ rb2, const int* __restrict__ p2,
    const int* __restrict__ s2,
    int* __restrict__ rank, float4* __restrict__ sorted)
{
    int e = blockIdx.x * 256 + threadIdx.x;
    if (e >= ET_) return;
    int kk, ia, ib, pp, ss;
    if (e < E1_) {
        kk = k1[e]; ia = r1[e]; pp = p1[e]; ss = s1[e]; ib = IB_ONE;
    } else {
        int i = e - E1_;
        kk = k2[i]; ia = ra2[i]; ib = rb2[i]; pp = p2[i]; ss = s2[i];
    }
    float a = alpha[kk], b = beta[kk], g = gam[kk];
    if (e < E1_ && kk < 2 * NSMT_) {
        ib = (kk < NSMT_) ? IB_KS : IB_KM;
        a = 1.0f; b = 0.0f; g = 0.0f;       // exp2(0)=1; coeff via wT row
    }
    float a_s = ss ? a : -a;
    int bits = ia | (ib << 10) | (pp << 20);
    int slot = atomicAdd(&rank[pp * PAD], 1);
    sorted[slot] = make_float4(a_s, b, g, __int_as_float(bits));
}

// ---------------------------------------------------------------------------
// Transpose in: yT[s][b] = y[b][s]; wT[s][b] = y[b][s]*den[b]; wT[800][b]=1.
// ---------------------------------------------------------------------------
__global__ __launch_bounds__(256) void transpose_kernel(
    const float* __restrict__ y, const float* __restrict__ den_gas,
    float* __restrict__ yT, float* __restrict__ wT)
{
    __shared__ float tile[32][33];
    const int sb = blockIdx.x % 25, bb = blockIdx.x / 25;
    const int tx = threadIdx.x & 31, ty = threadIdx.x >> 5;   // ty in [0,8)
    const int s0 = sb * 32, b0 = bb * 32;

    #pragma unroll
    for (int j = 0; j < 4; ++j) {
        int bl = ty + 8 * j;
        tile[bl][tx] = y[(b0 + bl) * S_ + s0 + tx];    // coalesced along s
    }
    __syncthreads();
    const float d = den_gas[b0 + tx];
    #pragma unroll
    for (int j = 0; j < 4; ++j) {
        int sl = ty + 8 * j;
        float v = tile[tx][sl];
        yT[(s0 + sl) * B_ + b0 + tx] = v;              // coalesced along b
        wT[(s0 + sl) * B_ + b0 + tx] = v * d;
    }
    if (blockIdx.x == 0) wT[IB_ONE * B_ + threadIdx.x] = 1.0f;
}

// ---------------------------------------------------------------------------
// Pack+compact gain/loss streams: keep only p in [200,500).
// Block-aggregated compaction: per-wave ballot, LDS scan of 4 wave counts,
// ONE atomicAdd per block per stream (fixes round 6's 512us serialization).
// Segments: [0,15k)=g1, [15k,60k)=g2, [60k,75k)=l1, [75k,120k)=l2.
// ---------------------------------------------------------------------------
__global__ __launch_bounds__(256) void packgl_kernel(
    const float* __restrict__ alpha, const float* __restrict__ beta,
    const float* __restrict__ gam,
    const int* __restrict__ k1g, const int* __restrict__ r1g,
    const int* __restrict__ p1g, const int* __restrict__ s1g,
    const int* __restrict__ k2g, const int* __restrict__ ra2g,
    const int* __restrict__ rb2g, const int* __restrict__ p2g,
    const int* __restrict__ s2g,
    const int* __restrict__ k1l, const int* __restrict__ r1l,
    const int* __restrict__ p1l, const int* __restrict__ s1l,
    const int* __restrict__ k2l, const int* __restrict__ ra2l,
    const int* __restrict__ rb2l, const int* __restrict__ p2l,
    const int* __restrict__ s2l,
    int* __restrict__ glcnt, float4* __restrict__ glG, float4* __restrict__ glL)
{
    __shared__ int cntW[2][4];
    __shared__ int baseS[2];

    const int tid = threadIdx.x, lane = tid & 63, wid = tid >> 6;
    const int e = blockIdx.x * 256 + tid;

    int kk = 0, ia = 0, ib = 0, pp = -1, ss = 0, gl = 0;
    if (e < EGL_) {
        if (e < 15000)      { int i = e;         kk = k1g[i]; ia = r1g[i];  ib = IB_ONE;  pp = p1g[i]; ss = s1g[i]; gl = 0; }
        else if (e < 60000) { int i = e - 15000; kk = k2g[i]; ia = ra2g[i]; ib = rb2g[i]; pp = p2g[i]; ss = s2g[i]; gl = 0; }
        else if (e < 75000) { int i = e - 60000; kk = k1l[i]; ia = r1l[i];  ib = IB_ONE;  pp = p1l[i]; ss = s1l[i]; gl = 1; }
        else                { int i = e - 75000; kk = k2l[i]; ia = ra2l[i]; ib = rb2l[i]; pp = p2l[i]; ss = s2l[i]; gl = 1; }
    }
    const bool keep = (pp >= 200 && pp < 500);
    const bool kG = keep && (gl == 0);
    const bool kL = keep && (gl == 1);

    const unsigned long long mG = __ballot(kG);
    const unsigned long long mL = __ballot(kL);
    if (lane == 0) { cntW[0][wid] = __popcll(mG); cntW[1][wid] = __popcll(mL); }
    __syncthreads();
    if (tid < 2) {
        int s = 0;
        #pragma unroll
        for (int w = 0; w < 4; ++w) { int v = cntW[tid][w]; cntW[tid][w] = s; s += v; }
        baseS[tid] = s ? atomicAdd(&glcnt[tid], s) : 0;
    }
    __syncthreads();

    if (keep) {
        float a = alpha[kk], b = beta[kk], g = gam[kk];
        float a_s = ss ? a : -a;
        int bits = ia | (ib << 10);
        const unsigned long long lt = (1ull << lane) - 1ull;
        if (kG) {
            int slot = baseS[0] + cntW[0][wid] + __popcll(mG & lt);
            glG[slot] = make_float4(a_s, b, g, __int_as_float(bits));
        } else {
            int slot = baseS[1] + cntW[1][wid] + __popcll(mL & lt);
            glL[slot] = make_float4(a_s, b, g, __int_as_float(bits));
        }
    }
}

// ---------------------------------------------------------------------------
// unified edge term (indices scalarized via readfirstlane; loads coalesced)
// ---------------------------------------------------------------------------
__device__ __forceinline__ float edge_term(
    float4 q, int t, const float* __restrict__ yT, const float* __restrict__ wT,
    float lt2, float nivt)
{
    int bu = __builtin_amdgcn_readfirstlane(__float_as_int(q.w));
    int ia = bu & 1023, ib = (bu >> 10) & 1023;
    return q.x * FAST_EXP2(fmaf(q.y, lt2, q.z * nivt))
         * yT[ia * B_ + t] * wT[ib * B_ + t];
}

// ---------------------------------------------------------------------------
// K1: gain/loss sums.  grid = NBGL_; thread = batch; LDS-staged chunks;
// sliced atomics into part_sl[NSL_][2*B].
// ---------------------------------------------------------------------------
__global__ __launch_bounds__(256) void gainloss_kernel(
    const float* __restrict__ T_gas,
    const float* __restrict__ yT, const float* __restrict__ wT,
    const float4* __restrict__ glG, const float4* __restrict__ glL,
    const int* __restrict__ glcnt,
    float* __restrict__ part_sl)
{
    __shared__ float4 tG[CAP_ / NBGL_], tL[CAP_ / NBGL_];   // 32 each
    const int t = threadIdx.x, c = blockIdx.x;
    const int nG = glcnt[0], nL = glcnt[1];
    const int cG = (nG + NBGL_ - 1) >> 10;
    const int cL = (nL + NBGL_ - 1) >> 10;
    const int g0 = c * cG, gn = min(nG, g0 + cG) - g0;
    const int l0 = c * cL, ln = min(nL, l0 + cL) - l0;
    for (int i = t; i < gn; i += 256) tG[i] = glG[g0 + i];
    for (int i = t; i < ln; i += 256) tL[i] = glL[l0 + i];
    __syncthreads();

    const float T    = T_gas[t];
    const float lt2  = log2f(T * (1.0f / 300.0f));
    const float nivt = -LOG2E_ / T;

    float gain = 0.f, loss = 0.f;
    #pragma unroll 4
    for (int i = 0; i < gn; ++i) gain += edge_term(tG[i], t, yT, wT, lt2, nivt);
    #pragma unroll 4
    for (int i = 0; i < ln; ++i) loss += edge_term(tL[i], t, yT, wT, lt2, nivt);

    float* sl = part_sl + (c & (NSL_ - 1)) * (2 * B_);
    atomicAdd(&sl[2 * t + 0], gain);
    atomicAdd(&sl[2 * t + 1], loss);
}

// ---------------------------------------------------------------------------
// ksm: per-batch k_s2m/k_m2s -> wT rows 801/802.  grid = B_ blocks, 64 thr.
// ---------------------------------------------------------------------------
__global__ __launch_bounds__(64) void ksm_kernel(
    const float* __restrict__ y, const float* __restrict__ part_sl,
    float* __restrict__ wT)
{
    const int b = blockIdx.x, lane = threadIdx.x;
    float vs = 0.f, vm = 0.f;
    #pragma unroll
    for (int j = 0; j < 5; ++j) {
        int i = lane + 64 * j;
        if (i < 300) { vs += y[b * S_ + 200 + i]; vm += y[b * S_ + 500 + i]; }
    }
    #pragma unroll
    for (int o = 32; o > 0; o >>= 1) {
        vs += __shfl_down(vs, o, 64);
        vm += __shfl_down(vm, o, 64);
    }
    if (lane == 0) {
        float gain = 0.f, loss = 0.f;
        #pragma unroll
        for (int s = 0; s < NSL_; ++s) {
            gain += part_sl[s * (2 * B_) + 2 * b + 0];
            loss += part_sl[s * (2 * B_) + 2 * b + 1];
        }
        float nl = 1e-2f * (vs + vm);
        float decay = fminf(2.0f / fmaxf(nl, EPS_), 1.0f);
        wT[IB_KS * B_ + b] = gain / fmaxf(vs, EPS_);
        wT[IB_KM * B_ + b] = loss / fmaxf(vm, EPS_) * decay;
    }
}

// ---------------------------------------------------------------------------
// K2: final RHS.  grid = NBF_ uniform 120-edge chunks of the sorted stream;
// thread = batch; LDS-staged chunk; flush-on-p-change into outT[p][b]
// (coalesced atomicAdd; outT pre-zeroed).
// ---------------------------------------------------------------------------
__global__ __launch_bounds__(256) void final_kernel(
    const float* __restrict__ T_gas,
    const float* __restrict__ yT, const float* __restrict__ wT,
    const float4* __restrict__ sorted,
    float* __restrict__ outT)
{
    __shared__ float4 tile[EPB_];
    const int t = threadIdx.x, c = blockIdx.x;
    const int e0 = c * EPB_;
    for (int i = t; i < EPB_; i += 256) tile[i] = sorted[e0 + i];
    __syncthreads();

    const float T    = T_gas[t];
    const float lt2  = log2f(T * (1.0f / 300.0f));
    const float nivt = -LOG2E_ / T;

    int pcur = -1;
    float acc = 0.f;
    #pragma unroll 1
    for (int i = 0; i < EPB_; i += 4) {
        float4 q0 = tile[i + 0], q1 = tile[i + 1];
        float4 q2 = tile[i + 2], q3 = tile[i + 3];
        int b0 = __builtin_amdgcn_readfirstlane(__float_as_int(q0.w));
        int b1 = __builtin_amdgcn_readfirstlane(__float_as_int(q1.w));
        int b2 = __builtin_amdgcn_readfirstlane(__float_as_int(q2.w));
        int b3 = __builtin_amdgcn_readfirstlane(__float_as_int(q3.w));
        // 8 independent coalesced loads issued together
        float y0 = yT[(b0 & 1023) * B_ + t], w0 = wT[((b0 >> 10) & 1023) * B_ + t];
        float y1 = yT[(b1 & 1023) * B_ + t], w1 = wT[((b1 >> 10) & 1023) * B_ + t];
        float y2 = yT[(b2 & 1023) * B_ + t], w2 = wT[((b2 >> 10) & 1023) * B_ + t];
        float y3 = yT[(b3 & 1023) * B_ + t], w3 = wT[((b3 >> 10) & 1023) * B_ + t];
        float t0 = q0.x * FAST_EXP2(fmaf(q0.y, lt2, q0.z * nivt)) * y0 * w0;
        float t1 = q1.x * FAST_EXP2(fmaf(q1.y, lt2, q1.z * nivt)) * y1 * w1;
        float t2 = q2.x * FAST_EXP2(fmaf(q2.y, lt2, q2.z * nivt)) * y2 * w2;
        float t3 = q3.x * FAST_EXP2(fmaf(q3.y, lt2, q3.z * nivt)) * y3 * w3;
        int p0 = b0 >> 20, p1 = b1 >> 20, p2 = b2 >> 20, p3 = b3 >> 20;
        if (p0 != pcur) { if (pcur >= 0) atomicAdd(&outT[pcur * B_ + t], acc); acc = 0.f; pcur = p0; }
        acc += t0;
        if (p1 != pcur) { atomicAdd(&outT[pcur * B_ + t], acc); acc = 0.f; pcur = p1; }
        acc += t1;
        if (p2 != pcur) { atomicAdd(&outT[pcur * B_ + t], acc); acc = 0.f; pcur = p2; }
        acc += t2;
        if (p3 != pcur) { atomicAdd(&outT[pcur * B_ + t], acc); acc = 0.f; pcur = p3; }
        acc += t3;
    }
    atomicAdd(&outT[pcur * B_ + t], acc);
}

// ---------------------------------------------------------------------------
// Transpose out: out[b][s] = outT[s][b].
// ---------------------------------------------------------------------------
__global__ __launch_bounds__(256) void transpose_out_kernel(
    const float* __restrict__ outT, float* __restrict__ out)
{
    __shared__ float tile[32][33];
    const int sb = blockIdx.x % 25, bb = blockIdx.x / 25;
    const int tx = threadIdx.x & 31, ty = threadIdx.x >> 5;
    const int s0 = sb * 32, b0 = bb * 32;

    #pragma unroll
    for (int j = 0; j < 4; ++j) {
        int sl = ty + 8 * j;
        tile[sl][tx] = outT[(s0 + sl) * B_ + b0 + tx];   // coalesced along b
    }
    __syncthreads();
    #pragma unroll
    for (int j = 0; j < 4; ++j) {
        int bl = ty + 8 * j;
        out[(b0 + bl) * S_ + s0 + tx] = tile[tx][bl];    // coalesced along s
    }
}

// ---------------------------------------------------------------------------
extern "C" void kernel_launch(void* const* d_in, const int* in_sizes, int n_in,
                              void* d_out, int out_size, void* d_ws, size_t ws_size,
                              hipStream_t stream) {
    const float* y       = (const float*)d_in[1];
    const float* den_gas = (const float*)d_in[2];
    const float* T_gas   = (const float*)d_in[3];
    const float* alpha   = (const float*)d_in[4];
    const float* beta    = (const float*)d_in[5];
    const float* gam     = (const float*)d_in[6];
    const int* k1  = (const int*)d_in[7];
    const int* r1  = (const int*)d_in[8];
    const int* p1  = (const int*)d_in[9];
    const int* s1  = (const int*)d_in[10];
    const int* k2  = (const int*)d_in[11];
    const int* ra2 = (const int*)d_in[12];
    const int* rb2 = (const int*)d_in[13];
    const int* p2  = (const int*)d_in[14];
    const int* s2  = (const int*)d_in[15];
    const int* k1g  = (const int*)d_in[16];
    const int* r1g  = (const int*)d_in[17];
    const int* p1g  = (const int*)d_in[18];
    const int* s1g  = (const int*)d_in[19];
    const int* k2g  = (const int*)d_in[20];
    const int* ra2g = (const int*)d_in[21];
    const int* rb2g = (const int*)d_in[22];
    const int* p2g  = (const int*)d_in[23];
    const int* s2g  = (const int*)d_in[24];
    const int* k1l  = (const int*)d_in[25];
    const int* r1l  = (const int*)d_in[26];
    const int* p1l  = (const int*)d_in[27];
    const int* s1l  = (const int*)d_in[28];
    const int* k2l  = (const int*)d_in[29];
    const int* ra2l = (const int*)d_in[30];
    const int* rb2l = (const int*)d_in[31];
    const int* p2l  = (const int*)d_in[32];
    const int* s2l  = (const int*)d_in[33];

    // workspace layout (~7.4 MB); ZERO region is contiguous (one memset)
    char* wsp = (char*)d_ws;
    size_t off = 0;
    float4* sorted = (float4*)(wsp + off); off += (size_t)ET_ * 16;        // 3,840,000
    float4* glG    = (float4*)(wsp + off); off += (size_t)CAP_ * 16;       //   524,288
    float4* glL    = (float4*)(wsp + off); off += (size_t)CAP_ * 16;       //   524,288
    float*  yT     = (float*)(wsp + off);  off += (size_t)S_ * B_ * 4;     //   819,200
    float*  wT     = (float*)(wsp + off);  off += (size_t)WROWS * B_ * 4;  //   823,296
    // ---- zero region start ----
    size_t zoff = off;
    float*  outT    = (float*)(wsp + off); off += (size_t)S_ * B_ * 4;     //   819,200
    int*    cntrank = (int*)(wsp + off);   off += (size_t)S_ * PAD * 4;    //    51,200
    float*  part_sl = (float*)(wsp + off); off += (size_t)NSL_ * 2 * B_ * 4; //  16,384
    int*    glcnt   = (int*)(wsp + off);   off += 64;
    size_t zbytes = off - zoff;

    float* out = (float*)d_out;

    hipMemsetAsync(wsp + zoff, 0, zbytes, stream);

    // counting sort of final edges by product p (batch-independent)
    hist_kernel<<<(ET_ + 255) / 256, 256, 0, stream>>>(p1, p2, cntrank);
    scan_kernel<<<1, 1024, 0, stream>>>(cntrank);
    reorder_kernel<<<(ET_ + 255) / 256, 256, 0, stream>>>(
        alpha, beta, gam, k1, r1, p1, s1, k2, ra2, rb2, p2, s2, cntrank, sorted);

    // transposed y / w tables
    transpose_kernel<<<200, 256, 0, stream>>>(y, den_gas, yT, wT);

    // compacted gain/loss streams (block-aggregated compaction)
    packgl_kernel<<<(EGL_ + 255) / 256, 256, 0, stream>>>(
        alpha, beta, gam,
        k1g, r1g, p1g, s1g, k2g, ra2g, rb2g, p2g, s2g,
        k1l, r1l, p1l, s1l, k2l, ra2l, rb2l, p2l, s2l,
        glcnt, glG, glL);

    // gain/loss scalars
    gainloss_kernel<<<NBGL_, 256, 0, stream>>>(T_gas, yT, wT, glG, glL, glcnt, part_sl);
    ksm_kernel<<<B_, 64, 0, stream>>>(y, part_sl, wT);

    // final assembly into outT, then transpose to out
    final_kernel<<<NBF_, 256, 0, stream>>>(T_gas, yT, wT, sorted, outT);
    transpose_out_kernel<<<200, 256, 0, stream>>>(outT, out);
}

// Round 8
// 88.251 us; speedup vs baseline: 6.8948x; 1.1508x over previous
//
#include <hip/hip_runtime.h>

// ThreePhaseTerm: sparse chemistry RHS assembly on MI355X.
//
// Round-8 = round-7 with dispatch fusion + deeper final ILP:
//   - prep_kernel fuses {hist, transpose, packgl} (independent, grid-
//     partitioned by blockIdx range).
//   - work_kernel fuses {reorder, gainloss} (independent after scan/prep).
//   - scan: single-sync shuffle scan (256 thr x 4 bins) replacing 20-barrier
//     Hillis-Steele.
//   - final: 8x unroll (15 rounds of 16 independent loads vs 30 of 8).
//   - ksm reshaped to 64 blocks x 256 thr.
//   7 dispatches total (memset + 6 kernels) vs 11 in round 7.
// Core structure unchanged: thread = batch; yT[s][b], wT[s][b] tables
// (wT rows 800/801/802 = 1/k_s2m/k_m2s); counting-sorted final edge stream
// with p in record bits[20..29]; flush-on-p-change atomics into outT[p][b];
// block-aggregated gl compaction (p in [200,500) only).

constexpr int B_    = 256;
constexpr int S_    = 800;
constexpr int E1_   = 60000;
constexpr int E2_   = 180000;
constexpr int ET_   = E1_ + E2_;      // 240000 final edges
constexpr int EGL_  = 120000;         // gain/loss edges before compaction
constexpr int NSMT_ = 600;
constexpr float LOG2E_ = 1.4426950408889634f;
constexpr float EPS_   = 1e-30f;
constexpr int PAD   = 16;             // int stride for sort counters
constexpr int CAP_  = 32768;          // per-stream gl capacity (exp ~22500)
constexpr int NBF_  = 2000;           // final blocks
constexpr int EPB_  = ET_ / NBF_;     // 120 edges per final block (exact)
constexpr int NBGL_ = 1024;           // gainloss blocks
constexpr int NSL_  = 8;              // partial slices for part accumulation
// prep kernel block partition
constexpr int NB_H  = (ET_ + 255) / 256;    // 938 hist blocks
constexpr int NB_T  = 200;                  // transpose blocks
constexpr int NB_P  = (EGL_ + 255) / 256;   // 469 packgl blocks
// work kernel block partition
constexpr int NB_R  = (ET_ + 255) / 256;    // 938 reorder blocks
// unified second-operand rows in wT
constexpr int IB_ONE = 800, IB_KS = 801, IB_KM = 802, WROWS = 804;

#if defined(__has_builtin)
#if __has_builtin(__builtin_amdgcn_exp2f)
#define FAST_EXP2(x) __builtin_amdgcn_exp2f(x)
#endif
#endif
#ifndef FAST_EXP2
#define FAST_EXP2(x) exp2f(x)
#endif

// ---------------------------------------------------------------------------
// prep: fused {hist | transpose | packgl}, partitioned by blockIdx.
// ---------------------------------------------------------------------------
__global__ __launch_bounds__(256) void prep_kernel(
    // hist
    const int* __restrict__ p1, const int* __restrict__ p2,
    int* __restrict__ cnt,
    // transpose
    const float* __restrict__ y, const float* __restrict__ den_gas,
    float* __restrict__ yT, float* __restrict__ wT,
    // packgl
    const float* __restrict__ alpha, const float* __restrict__ beta,
    const float* __restrict__ gam,
    const int* __restrict__ k1g, const int* __restrict__ r1g,
    const int* __restrict__ p1g, const int* __restrict__ s1g,
    const int* __restrict__ k2g, const int* __restrict__ ra2g,
    const int* __restrict__ rb2g, const int* __restrict__ p2g,
    const int* __restrict__ s2g,
    const int* __restrict__ k1l, const int* __restrict__ r1l,
    const int* __restrict__ p1l, const int* __restrict__ s1l,
    const int* __restrict__ k2l, const int* __restrict__ ra2l,
    const int* __restrict__ rb2l, const int* __restrict__ p2l,
    const int* __restrict__ s2l,
    int* __restrict__ glcnt, float4* __restrict__ glG, float4* __restrict__ glL)
{
    __shared__ float tile[32][33];
    __shared__ int cntW[2][4];
    __shared__ int baseS[2];

    const int blk = blockIdx.x;
    const int tid = threadIdx.x;

    if (blk < NB_H) {
        // ---------------- hist ----------------
        int e = blk * 256 + tid;
        if (e < E1_)      atomicAdd(&cnt[p1[e] * PAD], 1);
        else if (e < ET_) atomicAdd(&cnt[p2[e - E1_] * PAD], 1);
        return;
    }
    if (blk < NB_H + NB_T) {
        // ---------------- transpose ----------------
        const int bi = blk - NB_H;
        const int sb = bi % 25, bb = bi / 25;
        const int tx = tid & 31, ty = tid >> 5;          // ty in [0,8)
        const int s0 = sb * 32, b0 = bb * 32;
        #pragma unroll
        for (int j = 0; j < 4; ++j) {
            int bl = ty + 8 * j;
            tile[bl][tx] = y[(b0 + bl) * S_ + s0 + tx];  // coalesced along s
        }
        __syncthreads();
        const float d = den_gas[b0 + tx];
        #pragma unroll
        for (int j = 0; j < 4; ++j) {
            int sl = ty + 8 * j;
            float v = tile[tx][sl];
            yT[(s0 + sl) * B_ + b0 + tx] = v;            // coalesced along b
            wT[(s0 + sl) * B_ + b0 + tx] = v * d;
        }
        if (bi == 0) wT[IB_ONE * B_ + tid] = 1.0f;
        return;
    }
    // ---------------- packgl (block-aggregated compaction) ----------------
    {
        const int lane = tid & 63, wid = tid >> 6;
        const int e = (blk - NB_H - NB_T) * 256 + tid;

        int kk = 0, ia = 0, ib = 0, pp = -1, ss = 0, gl = 0;
        if (e < EGL_) {
            if (e < 15000)      { int i = e;         kk = k1g[i]; ia = r1g[i];  ib = IB_ONE;  pp = p1g[i]; ss = s1g[i]; gl = 0; }
            else if (e < 60000) { int i = e - 15000; kk = k2g[i]; ia = ra2g[i]; ib = rb2g[i]; pp = p2g[i]; ss = s2g[i]; gl = 0; }
            else if (e < 75000) { int i = e - 60000; kk = k1l[i]; ia = r1l[i];  ib = IB_ONE;  pp = p1l[i]; ss = s1l[i]; gl = 1; }
            else                { int i = e - 75000; kk = k2l[i]; ia = ra2l[i]; ib = rb2l[i]; pp = p2l[i]; ss = s2l[i]; gl = 1; }
        }
        const bool keep = (pp >= 200 && pp < 500);
        const bool kG = keep && (gl == 0);
        const bool kL = keep && (gl == 1);

        const unsigned long long mG = __ballot(kG);
        const unsigned long long mL = __ballot(kL);
        if (lane == 0) { cntW[0][wid] = __popcll(mG); cntW[1][wid] = __popcll(mL); }
        __syncthreads();
        if (tid < 2) {
            int s = 0;
            #pragma unroll
            for (int w = 0; w < 4; ++w) { int v = cntW[tid][w]; cntW[tid][w] = s; s += v; }
            baseS[tid] = s ? atomicAdd(&glcnt[tid], s) : 0;
        }
        __syncthreads();

        if (keep) {
            float a = alpha[kk], b = beta[kk], g = gam[kk];
            float a_s = ss ? a : -a;
            int bits = ia | (ib << 10);
            const unsigned long long lt = (1ull << lane) - 1ull;
            if (kG) {
                int slot = baseS[0] + cntW[0][wid] + __popcll(mG & lt);
                glG[slot] = make_float4(a_s, b, g, __int_as_float(bits));
            } else {
                int slot = baseS[1] + cntW[1][wid] + __popcll(mL & lt);
                glL[slot] = make_float4(a_s, b, g, __int_as_float(bits));
            }
        }
    }
}

// ---------------------------------------------------------------------------
// scan: exclusive scan of 800 PAD-strided bins in place.  1 block, 256 thr,
// 4 bins/thread, wave shuffle scan + 1 LDS stage (2 barriers total).
// ---------------------------------------------------------------------------
__global__ __launch_bounds__(256) void scan_kernel(int* __restrict__ cntrank)
{
    __shared__ int wsum[4];
    const int t = threadIdx.x, lane = t & 63, wid = t >> 6;

    int v[4];
    #pragma unroll
    for (int i = 0; i < 4; ++i) {
        int b = 4 * t + i;
        v[i] = (b < S_) ? cntrank[b * PAD] : 0;
    }
    int local = v[0] + v[1] + v[2] + v[3];

    // inclusive shuffle scan across the wave
    int x = local;
    #pragma unroll
    for (int o = 1; o < 64; o <<= 1) {
        int yv = __shfl_up(x, o, 64);
        if (lane >= o) x += yv;
    }
    if (lane == 63) wsum[wid] = x;
    __syncthreads();
    int base = 0;
    for (int w = 0; w < wid; ++w) base += wsum[w];
    int excl = base + x - local;

    int e0 = excl, e1 = excl + v[0], e2 = e1 + v[1], e3 = e2 + v[2];
    int ev[4] = {e0, e1, e2, e3};
    #pragma unroll
    for (int i = 0; i < 4; ++i) {
        int b = 4 * t + i;
        if (b < S_) cntrank[b * PAD] = ev[i];
    }
}

// ---------------------------------------------------------------------------
// unified edge term (indices scalarized via readfirstlane; loads coalesced)
// ---------------------------------------------------------------------------
__device__ __forceinline__ float edge_term(
    float4 q, int t, const float* __restrict__ yT, const float* __restrict__ wT,
    float lt2, float nivt)
{
    int bu = __builtin_amdgcn_readfirstlane(__float_as_int(q.w));
    int ia = bu & 1023, ib = (bu >> 10) & 1023;
    return q.x * FAST_EXP2(fmaf(q.y, lt2, q.z * nivt))
         * yT[ia * B_ + t] * wT[ib * B_ + t];
}

// ---------------------------------------------------------------------------
// work: fused {reorder | gainloss}, partitioned by blockIdx.
// ---------------------------------------------------------------------------
__global__ __launch_bounds__(256) void work_kernel(
    // reorder
    const float* __restrict__ alpha, const float* __restrict__ beta,
    const float* __restrict__ gam,
    const int* __restrict__ k1, const int* __restrict__ r1,
    const int* __restrict__ p1, const int* __restrict__ s1,
    const int* __restrict__ k2, const int* __restrict__ ra2,
    const int* __restrict__ rb2, const int* __restrict__ p2,
    const int* __restrict__ s2,
    int* __restrict__ rank, float4* __restrict__ sorted,
    // gainloss
    const float* __restrict__ T_gas,
    const float* __restrict__ yT, const float* __restrict__ wT,
    const float4* __restrict__ glG, const float4* __restrict__ glL,
    const int* __restrict__ glcnt,
    float* __restrict__ part_sl)
{
    __shared__ float4 tG[CAP_ / NBGL_], tL[CAP_ / NBGL_];   // 32 each
    const int blk = blockIdx.x;
    const int tid = threadIdx.x;

    if (blk < NB_R) {
        // ---------------- reorder ----------------
        int e = blk * 256 + tid;
        if (e >= ET_) return;
        int kk, ia, ib, pp, ss;
        if (e < E1_) {
            kk = k1[e]; ia = r1[e]; pp = p1[e]; ss = s1[e]; ib = IB_ONE;
        } else {
            int i = e - E1_;
            kk = k2[i]; ia = ra2[i]; ib = rb2[i]; pp = p2[i]; ss = s2[i];
        }
        float a = alpha[kk], b = beta[kk], g = gam[kk];
        if (e < E1_ && kk < 2 * NSMT_) {
            ib = (kk < NSMT_) ? IB_KS : IB_KM;
            a = 1.0f; b = 0.0f; g = 0.0f;       // exp2(0)=1; coeff via wT row
        }
        float a_s = ss ? a : -a;
        int bits = ia | (ib << 10) | (pp << 20);
        int slot = atomicAdd(&rank[pp * PAD], 1);
        sorted[slot] = make_float4(a_s, b, g, __int_as_float(bits));
        return;
    }
    // ---------------- gainloss ----------------
    {
        const int t = tid, c = blk - NB_R;
        const int nG = glcnt[0], nL = glcnt[1];
        const int cG = (nG + NBGL_ - 1) >> 10;
        const int cL = (nL + NBGL_ - 1) >> 10;
        const int g0 = c * cG, gn = min(nG, g0 + cG) - g0;
        const int l0 = c * cL, ln = min(nL, l0 + cL) - l0;
        for (int i = t; i < gn; i += 256) tG[i] = glG[g0 + i];
        for (int i = t; i < ln; i += 256) tL[i] = glL[l0 + i];
        __syncthreads();

        const float T    = T_gas[t];
        const float lt2  = log2f(T * (1.0f / 300.0f));
        const float nivt = -LOG2E_ / T;

        float gain = 0.f, loss = 0.f;
        #pragma unroll 4
        for (int i = 0; i < gn; ++i) gain += edge_term(tG[i], t, yT, wT, lt2, nivt);
        #pragma unroll 4
        for (int i = 0; i < ln; ++i) loss += edge_term(tL[i], t, yT, wT, lt2, nivt);

        float* sl = part_sl + (c & (NSL_ - 1)) * (2 * B_);
        atomicAdd(&sl[2 * t + 0], gain);
        atomicAdd(&sl[2 * t + 1], loss);
    }
}

// ---------------------------------------------------------------------------
// ksm: per-batch k_s2m/k_m2s -> wT rows 801/802.  64 blocks x 256 thr
// (wave wid handles batch blk*4+wid).
// ---------------------------------------------------------------------------
__global__ __launch_bounds__(256) void ksm_kernel(
    const float* __restrict__ y, const float* __restrict__ part_sl,
    float* __restrict__ wT)
{
    const int lane = threadIdx.x & 63, wid = threadIdx.x >> 6;
    const int b = blockIdx.x * 4 + wid;
    float vs = 0.f, vm = 0.f;
    #pragma unroll
    for (int j = 0; j < 5; ++j) {
        int i = lane + 64 * j;
        if (i < 300) { vs += y[b * S_ + 200 + i]; vm += y[b * S_ + 500 + i]; }
    }
    #pragma unroll
    for (int o = 32; o > 0; o >>= 1) {
        vs += __shfl_down(vs, o, 64);
        vm += __shfl_down(vm, o, 64);
    }
    if (lane == 0) {
        float gain = 0.f, loss = 0.f;
        #pragma unroll
        for (int s = 0; s < NSL_; ++s) {
            gain += part_sl[s * (2 * B_) + 2 * b + 0];
            loss += part_sl[s * (2 * B_) + 2 * b + 1];
        }
        float nl = 1e-2f * (vs + vm);
        float decay = fminf(2.0f / fmaxf(nl, EPS_), 1.0f);
        wT[IB_KS * B_ + b] = gain / fmaxf(vs, EPS_);
        wT[IB_KM * B_ + b] = loss / fmaxf(vm, EPS_) * decay;
    }
}

// ---------------------------------------------------------------------------
// final: grid = NBF_ uniform 120-edge chunks; thread = batch; LDS-staged
// chunk; 8x unroll; flush-on-p-change atomicAdd into outT[p][b] (pre-zeroed).
// ---------------------------------------------------------------------------
__global__ __launch_bounds__(256) void final_kernel(
    const float* __restrict__ T_gas,
    const float* __restrict__ yT, const float* __restrict__ wT,
    const float4* __restrict__ sorted,
    float* __restrict__ outT)
{
    __shared__ float4 tile[EPB_];
    const int t = threadIdx.x, c = blockIdx.x;
    const int e0 = c * EPB_;
    for (int i = t; i < EPB_; i += 256) tile[i] = sorted[e0 + i];
    __syncthreads();

    const float T    = T_gas[t];
    const float lt2  = log2f(T * (1.0f / 300.0f));
    const float nivt = -LOG2E_ / T;

    int pcur = -1;
    float acc = 0.f;
    #pragma unroll 1
    for (int i = 0; i < EPB_; i += 8) {
        float4 q0 = tile[i + 0], q1 = tile[i + 1];
        float4 q2 = tile[i + 2], q3 = tile[i + 3];
        float4 q4 = tile[i + 4], q5 = tile[i + 5];
        float4 q6 = tile[i + 6], q7 = tile[i + 7];
        int b0 = __builtin_amdgcn_readfirstlane(__float_as_int(q0.w));
        int b1 = __builtin_amdgcn_readfirstlane(__float_as_int(q1.w));
        int b2 = __builtin_amdgcn_readfirstlane(__float_as_int(q2.w));
        int b3 = __builtin_amdgcn_readfirstlane(__float_as_int(q3.w));
        int b4 = __builtin_amdgcn_readfirstlane(__float_as_int(q4.w));
        int b5 = __builtin_amdgcn_readfirstlane(__float_as_int(q5.w));
        int b6 = __builtin_amdgcn_readfirstlane(__float_as_int(q6.w));
        int b7 = __builtin_amdgcn_readfirstlane(__float_as_int(q7.w));
        // 16 independent coalesced loads issued together
        float y0 = yT[(b0 & 1023) * B_ + t], w0 = wT[((b0 >> 10) & 1023) * B_ + t];
        float y1 = yT[(b1 & 1023) * B_ + t], w1 = wT[((b1 >> 10) & 1023) * B_ + t];
        float y2 = yT[(b2 & 1023) * B_ + t], w2 = wT[((b2 >> 10) & 1023) * B_ + t];
        float y3 = yT[(b3 & 1023) * B_ + t], w3 = wT[((b3 >> 10) & 1023) * B_ + t];
        float y4 = yT[(b4 & 1023) * B_ + t], w4 = wT[((b4 >> 10) & 1023) * B_ + t];
        float y5 = yT[(b5 & 1023) * B_ + t], w5 = wT[((b5 >> 10) & 1023) * B_ + t];
        float y6 = yT[(b6 & 1023) * B_ + t], w6 = wT[((b6 >> 10) & 1023) * B_ + t];
        float y7 = yT[(b7 & 1023) * B_ + t], w7 = wT[((b7 >> 10) & 1023) * B_ + t];
        float t0 = q0.x * FAST_EXP2(fmaf(q0.y, lt2, q0.z * nivt)) * y0 * w0;
        float t1 = q1.x * FAST_EXP2(fmaf(q1.y, lt2, q1.z * nivt)) * y1 * w1;
        float t2 = q2.x * FAST_EXP2(fmaf(q2.y, lt2, q2.z * nivt)) * y2 * w2;
        float t3 = q3.x * FAST_EXP2(fmaf(q3.y, lt2, q3.z * nivt)) * y3 * w3;
        float t4 = q4.x * FAST_EXP2(fmaf(q4.y, lt2, q4.z * nivt)) * y4 * w4;
        float t5 = q5.x * FAST_EXP2(fmaf(q5.y, lt2, q5.z * nivt)) * y5 * w5;
        float t6 = q6.x * FAST_EXP2(fmaf(q6.y, lt2, q6.z * nivt)) * y6 * w6;
        float t7 = q7.x * FAST_EXP2(fmaf(q7.y, lt2, q7.z * nivt)) * y7 * w7;
        int p0 = b0 >> 20, p1 = b1 >> 20, p2 = b2 >> 20, p3 = b3 >> 20;
        int p4 = b4 >> 20, p5 = b5 >> 20, p6 = b6 >> 20, p7 = b7 >> 20;
        if (p0 != pcur) { if (pcur >= 0) atomicAdd(&outT[pcur * B_ + t], acc); acc = 0.f; pcur = p0; }
        acc += t0;
        if (p1 != pcur) { atomicAdd(&outT[pcur * B_ + t], acc); acc = 0.f; pcur = p1; }
        acc += t1;
        if (p2 != pcur) { atomicAdd(&outT[pcur * B_ + t], acc); acc = 0.f; pcur = p2; }
        acc += t2;
        if (p3 != pcur) { atomicAdd(&outT[pcur * B_ + t], acc); acc = 0.f; pcur = p3; }
        acc += t3;
        if (p4 != pcur) { atomicAdd(&outT[pcur * B_ + t], acc); acc = 0.f; pcur = p4; }
        acc += t4;
        if (p5 != pcur) { atomicAdd(&outT[pcur * B_ + t], acc); acc = 0.f; pcur = p5; }
        acc += t5;
        if (p6 != pcur) { atomicAdd(&outT[pcur * B_ + t], acc); acc = 0.f; pcur = p6; }
        acc += t6;
        if (p7 != pcur) { atomicAdd(&outT[pcur * B_ + t], acc); acc = 0.f; pcur = p7; }
        acc += t7;
    }
    atomicAdd(&outT[pcur * B_ + t], acc);
}

// ---------------------------------------------------------------------------
// Transpose out: out[b][s] = outT[s][b].
// ---------------------------------------------------------------------------
__global__ __launch_bounds__(256) void transpose_out_kernel(
    const float* __restrict__ outT, float* __restrict__ out)
{
    __shared__ float tile[32][33];
    const int sb = blockIdx.x % 25, bb = blockIdx.x / 25;
    const int tx = threadIdx.x & 31, ty = threadIdx.x >> 5;
    const int s0 = sb * 32, b0 = bb * 32;

    #pragma unroll
    for (int j = 0; j < 4; ++j) {
        int sl = ty + 8 * j;
        tile[sl][tx] = outT[(s0 + sl) * B_ + b0 + tx];   // coalesced along b
    }
    __syncthreads();
    #pragma unroll
    for (int j = 0; j < 4; ++j) {
        int bl = ty + 8 * j;
        out[(b0 + bl) * S_ + s0 + tx] = tile[tx][bl];    // coalesced along s
    }
}

// ---------------------------------------------------------------------------
extern "C" void kernel_launch(void* const* d_in, const int* in_sizes, int n_in,
                              void* d_out, int out_size, void* d_ws, size_t ws_size,
                              hipStream_t stream) {
    const float* y       = (const float*)d_in[1];
    const float* den_gas = (const float*)d_in[2];
    const float* T_gas   = (const float*)d_in[3];
    const float* alpha   = (const float*)d_in[4];
    const float* beta    = (const float*)d_in[5];
    const float* gam     = (const float*)d_in[6];
    const int* k1  = (const int*)d_in[7];
    const int* r1  = (const int*)d_in[8];
    const int* p1  = (const int*)d_in[9];
    const int* s1  = (const int*)d_in[10];
    const int* k2  = (const int*)d_in[11];
    const int* ra2 = (const int*)d_in[12];
    const int* rb2 = (const int*)d_in[13];
    const int* p2  = (const int*)d_in[14];
    const int* s2  = (const int*)d_in[15];
    const int* k1g  = (const int*)d_in[16];
    const int* r1g  = (const int*)d_in[17];
    const int* p1g  = (const int*)d_in[18];
    const int* s1g  = (const int*)d_in[19];
    const int* k2g  = (const int*)d_in[20];
    const int* ra2g = (const int*)d_in[21];
    const int* rb2g = (const int*)d_in[22];
    const int* p2g  = (const int*)d_in[23];
    const int* s2g  = (const int*)d_in[24];
    const int* k1l  = (const int*)d_in[25];
    const int* r1l  = (const int*)d_in[26];
    const int* p1l  = (const int*)d_in[27];
    const int* s1l  = (const int*)d_in[28];
    const int* k2l  = (const int*)d_in[29];
    const int* ra2l = (const int*)d_in[30];
    const int* rb2l = (const int*)d_in[31];
    const int* p2l  = (const int*)d_in[32];
    const int* s2l  = (const int*)d_in[33];

    // workspace layout (~7.4 MB); ZERO region is contiguous (one memset)
    char* wsp = (char*)d_ws;
    size_t off = 0;
    float4* sorted = (float4*)(wsp + off); off += (size_t)ET_ * 16;
    float4* glG    = (float4*)(wsp + off); off += (size_t)CAP_ * 16;
    float4* glL    = (float4*)(wsp + off); off += (size_t)CAP_ * 16;
    float*  yT     = (float*)(wsp + off);  off += (size_t)S_ * B_ * 4;
    float*  wT     = (float*)(wsp + off);  off += (size_t)WROWS * B_ * 4;
    // ---- zero region start ----
    size_t zoff = off;
    float*  outT    = (float*)(wsp + off); off += (size_t)S_ * B_ * 4;
    int*    cntrank = (int*)(wsp + off);   off += (size_t)S_ * PAD * 4;
    float*  part_sl = (float*)(wsp + off); off += (size_t)NSL_ * 2 * B_ * 4;
    int*    glcnt   = (int*)(wsp + off);   off += 64;
    size_t zbytes = off - zoff;

    float* out = (float*)d_out;

    hipMemsetAsync(wsp + zoff, 0, zbytes, stream);

    // prep: hist | transpose | packgl
    prep_kernel<<<NB_H + NB_T + NB_P, 256, 0, stream>>>(
        p1, p2, cntrank,
        y, den_gas, yT, wT,
        alpha, beta, gam,
        k1g, r1g, p1g, s1g, k2g, ra2g, rb2g, p2g, s2g,
        k1l, r1l, p1l, s1l, k2l, ra2l, rb2l, p2l, s2l,
        glcnt, glG, glL);

    // exclusive scan of product histogram (in place)
    scan_kernel<<<1, 256, 0, stream>>>(cntrank);

    // work: reorder | gainloss
    work_kernel<<<NB_R + NBGL_, 256, 0, stream>>>(
        alpha, beta, gam, k1, r1, p1, s1, k2, ra2, rb2, p2, s2,
        cntrank, sorted,
        T_gas, yT, wT, glG, glL, glcnt, part_sl);

    // per-batch swap coefficients
    ksm_kernel<<<64, 256, 0, stream>>>(y, part_sl, wT);

    // final assembly into outT, then transpose to out
    final_kernel<<<NBF_, 256, 0, stream>>>(T_gas, yT, wT, sorted, outT);
    transpose_out_kernel<<<200, 256, 0, stream>>>(outT, out);
}